// Round 1
// baseline (1284.541 us; speedup 1.0000x reference)
//
#include <hip/hip_runtime.h>
#include <math.h>

#define BB 8
#define CC 256
#define OO 256
#define HH 56
#define WW 56
#define HWH (HH*WW)        // 3136
#define RED 16
#define K2 9
#define KTOT (CC*K2)       // 2304

#define PXB 32             // pixels per block (deform_fused)
#define CCH 16             // channels per K-chunk
#define KLCH (CCH*K2)      // 144 K elements per chunk
#define ASTRIDE 36         // padded LDS stride (multiple of 4 for float4 reads)

// ---------------- SE: mean over H,W ----------------
__global__ __launch_bounds__(256) void se_mean(const float* __restrict__ x, float* __restrict__ y) {
    int bc = blockIdx.x;
    const float* p = x + (size_t)bc * HWH;
    float sum = 0.f;
    for (int i = threadIdx.x; i < HWH; i += 256) sum += p[i];
    __shared__ float sm[4];
    for (int off = 32; off > 0; off >>= 1) sum += __shfl_down(sum, off);
    if ((threadIdx.x & 63) == 0) sm[threadIdx.x >> 6] = sum;
    __syncthreads();
    if (threadIdx.x == 0) y[bc] = (sm[0] + sm[1] + sm[2] + sm[3]) * (1.0f / HWH);
}

// ---------------- SE: fc1->relu->fc2->sigmoid ----------------
__global__ __launch_bounds__(256) void se_fc(const float* __restrict__ y, const float* __restrict__ fc1,
                                             const float* __restrict__ fc2, float* __restrict__ s) {
    __shared__ float hbuf[BB * RED];   // 128
    int t = threadIdx.x;
    if (t < BB * RED) {
        int b = t / RED, r = t % RED;
        float acc = 0.f;
        for (int c = 0; c < CC; ++c) acc += y[b * CC + c] * fc1[r * CC + c];
        hbuf[t] = fmaxf(acc, 0.f);
    }
    __syncthreads();
    for (int i = t; i < BB * CC; i += 256) {
        int b = i / CC, c = i % CC;
        float acc = 0.f;
        #pragma unroll
        for (int r = 0; r < RED; ++r) acc += hbuf[b * RED + r] * fc2[c * RED + r];
        s[i] = 1.0f / (1.0f + expf(-acc));
    }
}

// ---------------- offset conv: 3x3, C=256 -> 18, zero pad, input scaled by s ----------------
__global__ __launch_bounds__(64) void offset_conv(const float* __restrict__ x, const float* __restrict__ s,
                                                  const float* __restrict__ w_off, const float* __restrict__ b_off,
                                                  float* __restrict__ offs) {
    int bid = blockIdx.x;
    int h = bid % HH;
    int m = (bid / HH) % 18;
    int b = bid / (HH * 18);
    int w = threadIdx.x;
    if (w >= WW) return;
    const float* xb = x + (size_t)b * CC * HWH;
    const float* sb = s + b * CC;
    const float* wm = w_off + m * CC * 9;
    float acc = 0.f;
    for (int c = 0; c < CC; ++c) {
        float sc = sb[c];
        const float* xc = xb + c * HWH;
        const float* wc = wm + c * 9;
        float a = 0.f;
        #pragma unroll
        for (int i = 0; i < 3; ++i) {
            int yy = h + i - 1;
            if (yy < 0 || yy >= HH) continue;
            #pragma unroll
            for (int j = 0; j < 3; ++j) {
                int xx = w + j - 1;
                if (xx < 0 || xx >= WW) continue;
                a += xc[yy * WW + xx] * wc[i * 3 + j];
            }
        }
        acc += a * sc;
    }
    offs[((b * 18 + m) * HWH) + h * WW + w] = acc + b_off[m];
}

// ---------------- transpose+scale: x_t[b][h][w][c] = x[b][c][h][w] * s[b][c] ----------------
__global__ __launch_bounds__(256) void transpose_scale(const float* __restrict__ x, const float* __restrict__ s,
                                                       float* __restrict__ x_t) {
    int bid = blockIdx.x;                 // B * (HW/64) = 8*49
    int b = bid / (HWH / 64);
    int hw = (bid % (HWH / 64)) * 64 + (threadIdx.x & 63);
    int cph = threadIdx.x >> 6;           // 0..3
    const float* xb = x + (size_t)b * CC * HWH;
    const float* sb = s + b * CC;
    float* xt = x_t + ((size_t)(b * HWH) + hw) * CC;
    for (int c = cph; c < CC; c += 4) {
        xt[c] = xb[(size_t)c * HWH + hw] * sb[c];
    }
}

// ---------------- weight transpose: w_t[k][o] = w_conv[o][k] ----------------
__global__ __launch_bounds__(256) void wt_prep(const float* __restrict__ w_conv, float* __restrict__ w_t) {
    int k = blockIdx.x;       // 0..2303
    int o = threadIdx.x;      // 0..255
    w_t[k * OO + o] = w_conv[(size_t)o * KTOT + k];
}

// ---------------- fused deformable conv GEMM (fp32 vector) ----------------
// block: 32 pixels x 256 outch; thread: 8 px x 4 o
__global__ __launch_bounds__(256) void deform_fused(const float* __restrict__ x_t, const float* __restrict__ offs,
                                                    const float* __restrict__ w_t, const float* __restrict__ b_conv,
                                                    float* __restrict__ out) {
    __shared__ __align__(16) float A[KLCH * ASTRIDE];   // 20736 B
    __shared__ int   cbs[4][PXB * 9];                   // 4608 B
    __shared__ float cws[4][PXB * 9];                   // 4608 B

    int bid = blockIdx.x;
    int b = bid / (HWH / PXB);                 // 98 tiles per image
    int hw0 = (bid % (HWH / PXB)) * PXB;
    int tid = threadIdx.x;

    // ---- per-(pixel,k) coordinate precompute ----
    for (int e = tid; e < PXB * 9; e += 256) {
        int px = e / 9, kk = e % 9;
        int hw = hw0 + px;
        int h = hw / WW, w = hw % WW;
        float dy = offs[((b * 18 + kk * 2 + 0) * HWH) + hw];
        float dx = offs[((b * 18 + kk * 2 + 1) * HWH) + hw];
        float ysf = (float)(h - 1 + kk / 3) + dy;
        float xsf = (float)(w - 1 + kk % 3) + dx;
        float y0f = floorf(ysf), x0f = floorf(xsf);
        float wy = ysf - y0f, wx = xsf - x0f;
        int y0 = (int)y0f, x0 = (int)x0f;
        #pragma unroll
        for (int j = 0; j < 4; ++j) {
            int yj = y0 + (j >> 1), xj = x0 + (j & 1);
            bool v = (yj >= 0) && (yj < HH) && (xj >= 0) && (xj < WW);
            int yc = min(max(yj, 0), HH - 1), xc = min(max(xj, 0), WW - 1);
            float wgt = ((j >> 1) ? wy : (1.f - wy)) * ((j & 1) ? wx : (1.f - wx));
            cws[j][e] = v ? wgt : 0.f;
            cbs[j][e] = (b * HWH + yc * WW + xc) * CC;
        }
    }
    __syncthreads();

    int tx = tid & 63;   // -> o0 = tx*4
    int ty = tid >> 6;   // -> p0 = ty*8
    float acc[8][4];
    #pragma unroll
    for (int p = 0; p < 8; ++p)
        #pragma unroll
        for (int i = 0; i < 4; ++i) acc[p][i] = 0.f;

    const float4* A4 = (const float4*)A;

    for (int cc = 0; cc < CC / CCH; ++cc) {     // 16 K-chunks
        // ---- stage sampled tile [144 kl][32 px] ----
        #pragma unroll
        for (int i2 = 0; i2 < (CCH * PXB * 9) / 256; ++i2) {   // 18
            int e = i2 * 256 + tid;
            int cl = e & 15;
            int pr = e >> 4;
            int px = pr & 31;
            int kk = pr >> 5;
            int ci = px * 9 + kk;
            int c = cc * CCH + cl;
            float v = cws[0][ci] * x_t[cbs[0][ci] + c]
                    + cws[1][ci] * x_t[cbs[1][ci] + c]
                    + cws[2][ci] * x_t[cbs[2][ci] + c]
                    + cws[3][ci] * x_t[cbs[3][ci] + c];
            A[(cl * 9 + kk) * ASTRIDE + px] = v;
        }
        __syncthreads();

        // ---- GEMM chunk ----
        int kbase = cc * KLCH;
        #pragma unroll 4
        for (int kl = 0; kl < KLCH; ++kl) {
            const float4 wv = *(const float4*)(w_t + (size_t)(kbase + kl) * OO + (tx << 2));
            const float4 a0 = A4[kl * 9 + (ty << 1)];
            const float4 a1 = A4[kl * 9 + (ty << 1) + 1];
            float av[8] = {a0.x, a0.y, a0.z, a0.w, a1.x, a1.y, a1.z, a1.w};
            float wvv[4] = {wv.x, wv.y, wv.z, wv.w};
            #pragma unroll
            for (int p = 0; p < 8; ++p)
                #pragma unroll
                for (int i = 0; i < 4; ++i)
                    acc[p][i] = fmaf(av[p], wvv[i], acc[p][i]);
        }
        __syncthreads();
    }

    // ---- epilogue: bias + tanh, NCHW out ----
    int o0 = tx << 2;
    int p0 = ty << 3;
    #pragma unroll
    for (int i = 0; i < 4; ++i) {
        float bo = b_conv[o0 + i];
        #pragma unroll
        for (int p = 0; p < 8; ++p) {
            out[((size_t)(b * OO + o0 + i)) * HWH + hw0 + p0 + p] = tanhf(acc[p][i] + bo);
        }
    }
}

// ---------------- fallback (small ws): direct per-pixel deform ----------------
__global__ __launch_bounds__(256) void deform_direct(const float* __restrict__ x, const float* __restrict__ s,
                                                     const float* __restrict__ offs, const float* __restrict__ w_conv,
                                                     const float* __restrict__ b_conv, float* __restrict__ out) {
    int pix = blockIdx.x;             // b*HW + hw
    int b = pix / HWH, hw = pix % HWH;
    int h = hw / WW, w = hw % WW;
    __shared__ __align__(16) float samp[KTOT];
    int c = threadIdx.x;
    float sc = s[b * CC + c];
    const float* xc = x + ((size_t)(b * CC + c)) * HWH;
    #pragma unroll
    for (int kk = 0; kk < 9; ++kk) {
        float dy = offs[((b * 18 + kk * 2 + 0) * HWH) + hw];
        float dx = offs[((b * 18 + kk * 2 + 1) * HWH) + hw];
        float ysf = (float)(h - 1 + kk / 3) + dy;
        float xsf = (float)(w - 1 + kk % 3) + dx;
        float y0f = floorf(ysf), x0f = floorf(xsf);
        float wy = ysf - y0f, wx = xsf - x0f;
        int y0 = (int)y0f, x0 = (int)x0f;
        float v = 0.f;
        #pragma unroll
        for (int j = 0; j < 4; ++j) {
            int yj = y0 + (j >> 1), xj = x0 + (j & 1);
            if (yj >= 0 && yj < HH && xj >= 0 && xj < WW) {
                float wgt = ((j >> 1) ? wy : (1.f - wy)) * ((j & 1) ? wx : (1.f - wx));
                v += wgt * xc[yj * WW + xj];
            }
        }
        samp[c * 9 + kk] = v * sc;
    }
    __syncthreads();
    int o = threadIdx.x;
    const float4* w4 = (const float4*)(w_conv + (size_t)o * KTOT);
    const float4* s4 = (const float4*)samp;
    float acc = 0.f;
    for (int i = 0; i < KTOT / 4; ++i) {
        float4 a = s4[i], wv = w4[i];
        acc += a.x * wv.x + a.y * wv.y + a.z * wv.z + a.w * wv.w;
    }
    out[((size_t)(b * OO + o)) * HWH + hw] = tanhf(acc + b_conv[o]);
}

extern "C" void kernel_launch(void* const* d_in, const int* in_sizes, int n_in,
                              void* d_out, int out_size, void* d_ws, size_t ws_size,
                              hipStream_t stream) {
    const float* x      = (const float*)d_in[0];
    const float* w_off  = (const float*)d_in[1];
    const float* b_off  = (const float*)d_in[2];
    const float* w_conv = (const float*)d_in[3];
    const float* b_conv = (const float*)d_in[4];
    const float* fc1    = (const float*)d_in[5];
    const float* fc2    = (const float*)d_in[6];
    float* out = (float*)d_out;
    float* ws  = (float*)d_ws;

    // ws layout (floats)
    float* y    = ws;                       // 2048
    float* s    = ws + 2048;                // 2048
    float* offs = ws + 4096;                // 451584
    float* w_t  = ws + 4096 + 451584;       // 589824
    float* x_t  = w_t + 589824;             // 6422528

    size_t need_full = (size_t)(2048 + 2048 + 451584 + 589824 + 6422528) * 4;
    bool full = ws_size >= need_full;

    se_mean<<<BB * CC, 256, 0, stream>>>(x, y);
    se_fc<<<1, 256, 0, stream>>>(y, fc1, fc2, s);
    offset_conv<<<BB * 18 * HH, 64, 0, stream>>>(x, s, w_off, b_off, offs);

    if (full) {
        wt_prep<<<KTOT, 256, 0, stream>>>(w_conv, w_t);
        transpose_scale<<<BB * (HWH / 64), 256, 0, stream>>>(x, s, x_t);
        deform_fused<<<BB * (HWH / PXB), 256, 0, stream>>>(x_t, offs, w_t, b_conv, out);
    } else {
        deform_direct<<<BB * HWH, 256, 0, stream>>>(x, s, offs, w_conv, b_conv, out);
    }
}

// Round 2
// 160.309 us; speedup vs baseline: 8.0129x; 8.0129x over previous
//
#include <hip/hip_runtime.h>
#include <math.h>

typedef __attribute__((ext_vector_type(8))) short short8;
typedef __attribute__((ext_vector_type(4))) float f32x4;

#define BB 8
#define CC 256
#define OO 256
#define HH 56
#define WW 56
#define HWH 3136
#define RED 16

__device__ inline unsigned short f2bf(float f) {
    unsigned u = __builtin_bit_cast(unsigned, f);
    u = (u + 0x7fffu + ((u >> 16) & 1u)) >> 16;
    return (unsigned short)u;
}
__device__ inline float bf2f(unsigned short h) {
    return __builtin_bit_cast(float, ((unsigned)h) << 16);
}

// ---------------- SE: mean over H,W ----------------
__global__ __launch_bounds__(256) void se_mean(const float* __restrict__ x, float* __restrict__ y) {
    int bc = blockIdx.x;
    const float4* p = (const float4*)(x + (size_t)bc * HWH);
    float sum = 0.f;
    for (int i = threadIdx.x; i < HWH / 4; i += 256) {
        float4 v = p[i];
        sum += v.x + v.y + v.z + v.w;
    }
    __shared__ float sm[4];
    for (int off = 32; off > 0; off >>= 1) sum += __shfl_down(sum, off);
    if ((threadIdx.x & 63) == 0) sm[threadIdx.x >> 6] = sum;
    __syncthreads();
    if (threadIdx.x == 0) y[bc] = (sm[0] + sm[1] + sm[2] + sm[3]) * (1.0f / HWH);
}

// ---------------- SE: fc1->relu->fc2->sigmoid ----------------
__global__ __launch_bounds__(256) void se_fc(const float* __restrict__ y, const float* __restrict__ fc1,
                                             const float* __restrict__ fc2, float* __restrict__ s) {
    __shared__ float hbuf[BB * RED];
    int t = threadIdx.x;
    if (t < BB * RED) {
        int b = t / RED, r = t % RED;
        float acc = 0.f;
        for (int c = 0; c < CC; ++c) acc += y[b * CC + c] * fc1[r * CC + c];
        hbuf[t] = fmaxf(acc, 0.f);
    }
    __syncthreads();
    for (int i = t; i < BB * CC; i += 256) {
        int b = i / CC, c = i % CC;
        float acc = 0.f;
        #pragma unroll
        for (int r = 0; r < RED; ++r) acc += hbuf[b * RED + r] * fc2[c * RED + r];
        s[i] = 1.0f / (1.0f + expf(-acc));
    }
}

// ---------------- NCHW f32 -> NHWC bf16, scaled by s ----------------
__global__ __launch_bounds__(256) void prep_xt(const float* __restrict__ x, const float* __restrict__ s,
                                               unsigned short* __restrict__ x_t) {
    __shared__ float t[64][65];
    int blk = blockIdx.x;
    int ct = blk & 3;
    int hwt = (blk >> 2) % 49;
    int b = blk / (4 * 49);
    int c0 = ct * 64, hw0 = hwt * 64;
    int tid = threadIdx.x;
    const float* xb = x + ((size_t)(b * CC + c0)) * HWH + hw0;
    #pragma unroll
    for (int it = 0; it < 16; ++it) {
        int idx = it * 256 + tid;
        int c = idx >> 6, px = idx & 63;
        t[c][px] = xb[(size_t)c * HWH + px];
    }
    __syncthreads();
    unsigned short* xo = x_t + ((size_t)(b * HWH + hw0)) * CC + c0;
    #pragma unroll
    for (int it = 0; it < 16; ++it) {
        int idx = it * 256 + tid;
        int px = idx >> 6, c = idx & 63;
        xo[(size_t)px * CC + c] = f2bf(t[c][px] * s[b * CC + c0 + c]);
    }
}

// ---------------- weight transposes -> [kk][o][c] bf16 ----------------
__global__ __launch_bounds__(256) void prep_wc(const float* __restrict__ w_conv, unsigned short* __restrict__ wb) {
    int idx = blockIdx.x * 256 + threadIdx.x;    // 9*256*256
    int kk = idx >> 16;
    int o = (idx >> 8) & 255;
    int c = idx & 255;
    wb[idx] = f2bf(w_conv[((o << 8) + c) * 9 + kk]);
}
__global__ __launch_bounds__(256) void prep_wo(const float* __restrict__ w_off, unsigned short* __restrict__ wb) {
    int idx = blockIdx.x * 256 + threadIdx.x;    // 9*32*256
    int kk = idx >> 13;
    int o = (idx >> 8) & 31;
    int c = idx & 255;
    wb[idx] = (o < 18) ? f2bf(w_off[((o << 8) + c) * 9 + kk]) : (unsigned short)0;
}

// ---------------- offset conv via MFMA: M=64px x N=32(pad18) x K=2304 ----------------
__global__ __launch_bounds__(256) void offset_mfma(const unsigned short* __restrict__ x_t,
                                                   const unsigned short* __restrict__ wb,
                                                   const float* __restrict__ b_off,
                                                   float* __restrict__ offs) {
    __shared__ __align__(16) char As[64 * 128];
    __shared__ __align__(16) char Bs2[32 * 128];
    int blk = blockIdx.x;
    int b = blk / 49;
    int hw0 = (blk % 49) * 64;
    int tid = threadIdx.x;
    int lane = tid & 63, wv = tid >> 6;
    f32x4 zero = {0.f, 0.f, 0.f, 0.f};
    f32x4 acc[2] = {zero, zero};
    for (int kk = 0; kk < 9; ++kk) {
        int di = kk / 3 - 1, dj = kk % 3 - 1;
        for (int cc = 0; cc < 4; ++cc) {
            int c0 = cc * 64;
            #pragma unroll
            for (int it = 0; it < 2; ++it) {
                int item = it * 256 + tid;
                int px = item >> 3, c8 = item & 7;
                int hw = hw0 + px, h = hw / 56, w = hw - h * 56;
                int hh = h + di, ww = w + dj;
                short8 v = {0, 0, 0, 0, 0, 0, 0, 0};
                if (hh >= 0 && hh < 56 && ww >= 0 && ww < 56)
                    v = *(const short8*)(x_t + (((size_t)(b * HWH + hh * 56 + ww)) << 8) + c0 + c8 * 8);
                int off = px * 128 + c8 * 16; off ^= (px & 7) << 4;
                *(short8*)(As + off) = v;
            }
            {
                int o = tid >> 3, c8 = tid & 7;
                short8 v = *(const short8*)(wb + kk * 8192 + o * 256 + c0 + c8 * 8);
                int off = o * 128 + c8 * 16; off ^= (o & 7) << 4;
                *(short8*)(Bs2 + off) = v;
            }
            __syncthreads();
            int arow = wv * 16 + (lane & 15);
            int kb = (lane >> 4) << 4;
            #pragma unroll
            for (int kh = 0; kh < 2; ++kh) {
                int ao = arow * 128 + kh * 64 + kb; ao ^= (arow & 7) << 4;
                short8 a = *(const short8*)(As + ao);
                #pragma unroll
                for (int n = 0; n < 2; ++n) {
                    int brow = n * 16 + (lane & 15);
                    int bo = brow * 128 + kh * 64 + kb; bo ^= (brow & 7) << 4;
                    short8 bv = *(const short8*)(Bs2 + bo);
                    acc[n] = __builtin_amdgcn_mfma_f32_16x16x32_bf16(a, bv, acc[n], 0, 0, 0);
                }
            }
            __syncthreads();
        }
    }
    int o_ = lane & 15;
    int prow = wv * 16 + ((lane >> 4) << 2);
    #pragma unroll
    for (int n = 0; n < 2; ++n) {
        int o = n * 16 + o_;
        if (o < 18) {
            float bia = b_off[o];
            #pragma unroll
            for (int r = 0; r < 4; ++r)
                offs[((size_t)(b * 18 + o)) * HWH + hw0 + prow + r] = acc[n][r] + bia;
        }
    }
}

// ---------------- deformable conv via MFMA: tile 64px x 256o, K=2304 ----------------
__global__ __launch_bounds__(512) void deform_mfma(const unsigned short* __restrict__ x_t,
                                                   const float* __restrict__ offs,
                                                   const unsigned short* __restrict__ wb,
                                                   const float* __restrict__ b_conv,
                                                   float* __restrict__ out) {
    __shared__ __align__(16) char As[64 * 128];     // 8 KB
    __shared__ __align__(16) char Bs2[256 * 128];   // 32 KB
    __shared__ int cbase[4][64];
    __shared__ float cwt[4][64];
    int blk = blockIdx.x;
    int b = blk / 49;
    int hw0 = (blk % 49) * 64;
    int tid = threadIdx.x;
    int lane = tid & 63, wv = tid >> 6;
    int wm = wv & 1, wn = wv >> 1;
    f32x4 zero = {0.f, 0.f, 0.f, 0.f};
    f32x4 acc[2][4];
    #pragma unroll
    for (int m = 0; m < 2; ++m)
        #pragma unroll
        for (int n = 0; n < 4; ++n) acc[m][n] = zero;

    for (int kk = 0; kk < 9; ++kk) {
        if (tid < 64) {
            int px = tid, hw = hw0 + px;
            int h = hw / 56, w = hw - h * 56;
            float dy = offs[((size_t)(b * 18 + kk * 2)) * HWH + hw];
            float dx = offs[((size_t)(b * 18 + kk * 2 + 1)) * HWH + hw];
            float ys = (float)(h - 1 + kk / 3) + dy;
            float xs = (float)(w - 1 + kk % 3) + dx;
            float y0f = floorf(ys), x0f = floorf(xs);
            float wy = ys - y0f, wx = xs - x0f;
            int y0 = (int)y0f, x0 = (int)x0f;
            #pragma unroll
            for (int j = 0; j < 4; ++j) {
                int yj = y0 + (j >> 1), xj = x0 + (j & 1);
                bool val = yj >= 0 && yj < 56 && xj >= 0 && xj < 56;
                int yc = min(max(yj, 0), 55), xc = min(max(xj, 0), 55);
                float wgt = ((j >> 1) ? wy : 1.f - wy) * ((j & 1) ? wx : 1.f - wx);
                cbase[j][px] = (b * HWH + yc * 56 + xc) << 8;
                cwt[j][px] = val ? wgt : 0.f;
            }
        }
        __syncthreads();
        for (int cc = 0; cc < 4; ++cc) {
            int c0 = cc * 64;
            // ---- stage A: bilinear-sampled 64px x 64ch, bf16, swizzled ----
            {
                int px = tid >> 3, c8 = tid & 7;
                int coff = c0 + c8 * 8;
                float f[8] = {0.f, 0.f, 0.f, 0.f, 0.f, 0.f, 0.f, 0.f};
                #pragma unroll
                for (int j = 0; j < 4; ++j) {
                    float wgt = cwt[j][px];
                    short8 v = *(const short8*)(x_t + cbase[j][px] + coff);
                    #pragma unroll
                    for (int e = 0; e < 8; ++e)
                        f[e] += wgt * bf2f((unsigned short)v[e]);
                }
                short8 r;
                #pragma unroll
                for (int e = 0; e < 8; ++e) r[e] = (short)f2bf(f[e]);
                int off = px * 128 + c8 * 16; off ^= (px & 7) << 4;
                *(short8*)(As + off) = r;
            }
            // ---- stage B: 256o x 64ch of wb[kk], swizzled ----
            #pragma unroll
            for (int it = 0; it < 4; ++it) {
                int item = it * 512 + tid;
                int o = item >> 3, c8 = item & 7;
                short8 v = *(const short8*)(wb + kk * 65536 + o * 256 + c0 + c8 * 8);
                int off = o * 128 + c8 * 16; off ^= (o & 7) << 4;
                *(short8*)(Bs2 + off) = v;
            }
            __syncthreads();
            // ---- MFMA: wave tile 32px x 64o ----
            int kb = (lane >> 4) << 4;
            short8 a[2][2];
            #pragma unroll
            for (int m = 0; m < 2; ++m)
                #pragma unroll
                for (int kh = 0; kh < 2; ++kh) {
                    int row = wm * 32 + m * 16 + (lane & 15);
                    int ao = row * 128 + kh * 64 + kb; ao ^= (row & 7) << 4;
                    a[m][kh] = *(const short8*)(As + ao);
                }
            #pragma unroll
            for (int n = 0; n < 4; ++n) {
                int brow = wn * 64 + n * 16 + (lane & 15);
                #pragma unroll
                for (int kh = 0; kh < 2; ++kh) {
                    int bo = brow * 128 + kh * 64 + kb; bo ^= (brow & 7) << 4;
                    short8 bv = *(const short8*)(Bs2 + bo);
                    #pragma unroll
                    for (int m = 0; m < 2; ++m)
                        acc[m][n] = __builtin_amdgcn_mfma_f32_16x16x32_bf16(a[m][kh], bv, acc[m][n], 0, 0, 0);
                }
            }
            __syncthreads();
        }
    }
    // ---- epilogue: bias + tanh, NCHW float4 stores ----
    int o_ = lane & 15;
    int pr = (lane >> 4) << 2;
    #pragma unroll
    for (int n = 0; n < 4; ++n) {
        int o = wn * 64 + n * 16 + o_;
        float bia = b_conv[o];
        #pragma unroll
        for (int m = 0; m < 2; ++m) {
            int px = hw0 + wm * 32 + m * 16 + pr;
            float4 v;
            v.x = tanhf(acc[m][n][0] + bia);
            v.y = tanhf(acc[m][n][1] + bia);
            v.z = tanhf(acc[m][n][2] + bia);
            v.w = tanhf(acc[m][n][3] + bia);
            *(float4*)(out + ((size_t)(b * OO + o)) * HWH + px) = v;
        }
    }
}

extern "C" void kernel_launch(void* const* d_in, const int* in_sizes, int n_in,
                              void* d_out, int out_size, void* d_ws, size_t ws_size,
                              hipStream_t stream) {
    const float* x      = (const float*)d_in[0];
    const float* w_off  = (const float*)d_in[1];
    const float* b_off  = (const float*)d_in[2];
    const float* w_conv = (const float*)d_in[3];
    const float* b_conv = (const float*)d_in[4];
    const float* fc1    = (const float*)d_in[5];
    const float* fc2    = (const float*)d_in[6];
    float* out = (float*)d_out;
    float* ws  = (float*)d_ws;

    float* y    = ws;                    // 2048
    float* s    = y + 2048;              // 2048
    float* offs = s + 2048;              // 8*18*3136 = 451584
    unsigned short* x_t  = (unsigned short*)(offs + 451584);  // 8*3136*256 bf16
    unsigned short* wb_c = x_t + 6422528;                     // 9*256*256
    unsigned short* wb_o = wb_c + 589824;                     // 9*32*256

    se_mean<<<BB * CC, 256, 0, stream>>>(x, y);
    se_fc<<<1, 256, 0, stream>>>(y, fc1, fc2, s);
    prep_wc<<<2304, 256, 0, stream>>>(w_conv, wb_c);
    prep_wo<<<288, 256, 0, stream>>>(w_off, wb_o);
    prep_xt<<<BB * 49 * 4, 256, 0, stream>>>(x, s, x_t);
    offset_mfma<<<BB * 49, 256, 0, stream>>>(x_t, wb_o, b_off, offs);
    deform_mfma<<<BB * 49, 512, 0, stream>>>(x_t, offs, wb_c, b_conv, out);
}

// Round 3
// 142.319 us; speedup vs baseline: 9.0258x; 1.1264x over previous
//
#include <hip/hip_runtime.h>
#include <math.h>

typedef __attribute__((ext_vector_type(8))) short short8;
typedef __attribute__((ext_vector_type(4))) float f32x4;

#define BB 8
#define CC 256
#define OO 256
#define HH 56
#define WW 56
#define HWH 3136
#define RED 16

__device__ inline unsigned short f2bf(float f) {
    unsigned u = __builtin_bit_cast(unsigned, f);
    u = (u + 0x7fffu + ((u >> 16) & 1u)) >> 16;
    return (unsigned short)u;
}
__device__ inline float bf2f(unsigned short h) {
    return __builtin_bit_cast(float, ((unsigned)h) << 16);
}
__device__ inline void gl2lds16(const void* g, void* l) {
    __builtin_amdgcn_global_load_lds((const __attribute__((address_space(1))) unsigned int*)g,
                                     (__attribute__((address_space(3))) unsigned int*)l, 16, 0, 0);
}

// ---------------- SE: mean over H,W ----------------
__global__ __launch_bounds__(256) void se_mean(const float* __restrict__ x, float* __restrict__ y) {
    int bc = blockIdx.x;
    const float4* p = (const float4*)(x + (size_t)bc * HWH);
    float sum = 0.f;
    for (int i = threadIdx.x; i < HWH / 4; i += 256) {
        float4 v = p[i];
        sum += v.x + v.y + v.z + v.w;
    }
    __shared__ float sm[4];
    for (int off = 32; off > 0; off >>= 1) sum += __shfl_down(sum, off);
    if ((threadIdx.x & 63) == 0) sm[threadIdx.x >> 6] = sum;
    __syncthreads();
    if (threadIdx.x == 0) y[bc] = (sm[0] + sm[1] + sm[2] + sm[3]) * (1.0f / HWH);
}

// ---------------- SE: fc1->relu->fc2->sigmoid ----------------
__global__ __launch_bounds__(256) void se_fc(const float* __restrict__ y, const float* __restrict__ fc1,
                                             const float* __restrict__ fc2, float* __restrict__ s) {
    __shared__ float hbuf[BB * RED];
    int t = threadIdx.x;
    if (t < BB * RED) {
        int b = t / RED, r = t % RED;
        float acc = 0.f;
        for (int c = 0; c < CC; ++c) acc += y[b * CC + c] * fc1[r * CC + c];
        hbuf[t] = fmaxf(acc, 0.f);
    }
    __syncthreads();
    for (int i = t; i < BB * CC; i += 256) {
        int b = i / CC, c = i % CC;
        float acc = 0.f;
        #pragma unroll
        for (int r = 0; r < RED; ++r) acc += hbuf[b * RED + r] * fc2[c * RED + r];
        s[i] = 1.0f / (1.0f + expf(-acc));
    }
}

// ---------------- NCHW f32 -> NHWC bf16, scaled by s ----------------
__global__ __launch_bounds__(256) void prep_xt(const float* __restrict__ x, const float* __restrict__ s,
                                               unsigned short* __restrict__ x_t) {
    __shared__ float t[64][65];
    int blk = blockIdx.x;
    int ct = blk & 3;
    int hwt = (blk >> 2) % 49;
    int b = blk / (4 * 49);
    int c0 = ct * 64, hw0 = hwt * 64;
    int tid = threadIdx.x;
    const float* xb = x + ((size_t)(b * CC + c0)) * HWH + hw0;
    #pragma unroll
    for (int it = 0; it < 16; ++it) {
        int idx = it * 256 + tid;
        int c = idx >> 6, px = idx & 63;
        t[c][px] = xb[(size_t)c * HWH + px];
    }
    __syncthreads();
    unsigned short* xo = x_t + ((size_t)(b * HWH + hw0)) * CC + c0;
    #pragma unroll
    for (int it = 0; it < 16; ++it) {
        int idx = it * 256 + tid;
        int px = idx >> 6, c = idx & 63;
        xo[(size_t)px * CC + c] = f2bf(t[c][px] * s[b * CC + c0 + c]);
    }
}

// ---------------- deform weights: pre-swizzled pack [kk][cc]{32KB tile} ----------------
// tile byte layout: for row o (0..255), 16B-group g (0..7): off = o*128+g*16, off ^= (o&7)<<4
__global__ __launch_bounds__(256) void prep_wc(const float* __restrict__ w_conv, unsigned short* __restrict__ wbp) {
    int idx = blockIdx.x * 256 + threadIdx.x;   // 9*4*256*8 = 73728
    int g = idx & 7;
    int o = (idx >> 3) & 255;
    int t = idx >> 11;        // kk*4+cc
    int cc = t & 3, kk = t >> 2;
    int off = o * 128 + g * 16; off ^= (o & 7) << 4;
    unsigned short* dst = wbp + (size_t)t * 16384 + (off >> 1);
    int cb = cc * 64 + g * 8;
    short8 r;
    #pragma unroll
    for (int e = 0; e < 8; ++e) r[e] = (short)f2bf(w_conv[(size_t)(o * 256 + cb + e) * 9 + kk]);
    *(short8*)dst = r;
}

// ---------------- offset weights -> [kk][o][c] bf16 (o padded to 32) ----------------
__global__ __launch_bounds__(256) void prep_wo(const float* __restrict__ w_off, unsigned short* __restrict__ wb) {
    int idx = blockIdx.x * 256 + threadIdx.x;    // 9*32*256
    int kk = idx >> 13;
    int o = (idx >> 8) & 31;
    int c = idx & 255;
    wb[idx] = (o < 18) ? f2bf(w_off[((o << 8) + c) * 9 + kk]) : (unsigned short)0;
}

// ---------------- offset conv via MFMA: M=64px x N=32(pad18) x K=2304 ----------------
__global__ __launch_bounds__(256) void offset_mfma(const unsigned short* __restrict__ x_t,
                                                   const unsigned short* __restrict__ wb,
                                                   const float* __restrict__ b_off,
                                                   float* __restrict__ offs) {
    __shared__ __align__(16) char As[64 * 128];
    __shared__ __align__(16) char Bs2[32 * 128];
    int blk = blockIdx.x;
    int b = blk / 49;
    int hw0 = (blk % 49) * 64;
    int tid = threadIdx.x;
    int lane = tid & 63, wv = tid >> 6;
    f32x4 zero = {0.f, 0.f, 0.f, 0.f};
    f32x4 acc[2] = {zero, zero};
    for (int kk = 0; kk < 9; ++kk) {
        int di = kk / 3 - 1, dj = kk % 3 - 1;
        for (int cc = 0; cc < 4; ++cc) {
            int c0 = cc * 64;
            #pragma unroll
            for (int it = 0; it < 2; ++it) {
                int item = it * 256 + tid;
                int px = item >> 3, c8 = item & 7;
                int hw = hw0 + px, h = hw / 56, w = hw - h * 56;
                int hh = h + di, ww = w + dj;
                short8 v = {0, 0, 0, 0, 0, 0, 0, 0};
                if (hh >= 0 && hh < 56 && ww >= 0 && ww < 56)
                    v = *(const short8*)(x_t + (((size_t)(b * HWH + hh * 56 + ww)) << 8) + c0 + c8 * 8);
                int off = px * 128 + c8 * 16; off ^= (px & 7) << 4;
                *(short8*)(As + off) = v;
            }
            {
                int o = tid >> 3, c8 = tid & 7;
                short8 v = *(const short8*)(wb + kk * 8192 + o * 256 + c0 + c8 * 8);
                int off = o * 128 + c8 * 16; off ^= (o & 7) << 4;
                *(short8*)(Bs2 + off) = v;
            }
            __syncthreads();
            int arow = wv * 16 + (lane & 15);
            int kb = (lane >> 4) << 4;
            #pragma unroll
            for (int kh = 0; kh < 2; ++kh) {
                int ao = arow * 128 + kh * 64 + kb; ao ^= (arow & 7) << 4;
                short8 a = *(const short8*)(As + ao);
                #pragma unroll
                for (int n = 0; n < 2; ++n) {
                    int brow = n * 16 + (lane & 15);
                    int bo = brow * 128 + kh * 64 + kb; bo ^= (brow & 7) << 4;
                    short8 bv = *(const short8*)(Bs2 + bo);
                    acc[n] = __builtin_amdgcn_mfma_f32_16x16x32_bf16(a, bv, acc[n], 0, 0, 0);
                }
            }
            __syncthreads();
        }
    }
    int o_ = lane & 15;
    int prow = wv * 16 + ((lane >> 4) << 2);
    #pragma unroll
    for (int n = 0; n < 2; ++n) {
        int o = n * 16 + o_;
        if (o < 18) {
            float bia = b_off[o];
            #pragma unroll
            for (int r = 0; r < 4; ++r)
                offs[((size_t)(b * 18 + o)) * HWH + hw0 + prow + r] = acc[n][r] + bia;
        }
    }
}

// ---------------- precompute bilinear coords: bases (int4) + weights (float4) ----------------
__global__ __launch_bounds__(256) void coords_prep(const float* __restrict__ offs,
                                                   int4* __restrict__ ci, float4* __restrict__ cf) {
    int idx = blockIdx.x * 256 + threadIdx.x;    // 8*9*3136 = 225792
    int hw = idx % 3136;
    int t = idx / 3136;
    int kk = t % 9;
    int b = t / 9;
    int h = hw / 56, w = hw - h * 56;
    float dy = offs[((size_t)(b * 18 + kk * 2)) * HWH + hw];
    float dx = offs[((size_t)(b * 18 + kk * 2 + 1)) * HWH + hw];
    float ys = (float)(h - 1 + kk / 3) + dy;
    float xs = (float)(w - 1 + kk % 3) + dx;
    float y0f = floorf(ys), x0f = floorf(xs);
    float wy = ys - y0f, wx = xs - x0f;
    int y0 = (int)y0f, x0 = (int)x0f;
    int bi[4]; float wt[4];
    #pragma unroll
    for (int j = 0; j < 4; ++j) {
        int yj = y0 + (j >> 1), xj = x0 + (j & 1);
        bool val = yj >= 0 && yj < 56 && xj >= 0 && xj < 56;
        int yc = min(max(yj, 0), 55), xc = min(max(xj, 0), 55);
        wt[j] = val ? ((j >> 1) ? wy : 1.f - wy) * ((j & 1) ? wx : 1.f - wx) : 0.f;
        bi[j] = (b * HWH + yc * 56 + xc) << 8;
    }
    ci[idx] = make_int4(bi[0], bi[1], bi[2], bi[3]);
    cf[idx] = make_float4(wt[0], wt[1], wt[2], wt[3]);
}

// ---------------- deformable conv via MFMA: tile 32px x 256o, 4 waves ----------------
__global__ __launch_bounds__(256, 4) void deform_mfma(const unsigned short* __restrict__ x_t,
                                                      const int4* __restrict__ ci,
                                                      const float4* __restrict__ cf,
                                                      const unsigned short* __restrict__ wbp,
                                                      const float* __restrict__ b_conv,
                                                      float* __restrict__ out) {
    __shared__ __align__(16) char As[32 * 128];     // 4 KB
    __shared__ __align__(16) char Bs[256 * 128];    // 32 KB
    int blk = blockIdx.x;
    blk = (blk & 7) * 98 + (blk >> 3);              // XCD-bijective swizzle (784 = 8*98)
    int b = blk / 98;
    int hw0 = (blk % 98) * 32;
    int tid = threadIdx.x;
    int lane = tid & 63, wv = tid >> 6;             // wv = o-group (wave tile 32px x 64o)
    int px = tid >> 3, c8 = tid & 7;                // A-stage roles
    f32x4 zero = {0.f, 0.f, 0.f, 0.f};
    f32x4 acc[2][4];
    #pragma unroll
    for (int m = 0; m < 2; ++m)
        #pragma unroll
        for (int n = 0; n < 4; ++n) acc[m][n] = zero;

    for (int kk = 0; kk < 9; ++kk) {
        int cidx = (b * 9 + kk) * HWH + hw0 + px;
        int4 cb = ci[cidx];
        float4 cw = cf[cidx];
        for (int cc = 0; cc < 4; ++cc) {
            // ---- B stage: async copy 32 KB (pre-swizzled in global) ----
            {
                const char* src = (const char*)wbp + (size_t)(kk * 4 + cc) * 32768 + wv * 8192 + (lane << 4);
                #pragma unroll
                for (int it = 0; it < 8; ++it)
                    gl2lds16(src + it * 1024, Bs + wv * 8192 + it * 1024);
            }
            // ---- A stage: bilinear 32px x 64ch -> bf16 swizzled ----
            {
                int c0 = cc * 64 + c8 * 8;
                short8 v0 = *(const short8*)(x_t + cb.x + c0);
                short8 v1 = *(const short8*)(x_t + cb.y + c0);
                short8 v2 = *(const short8*)(x_t + cb.z + c0);
                short8 v3 = *(const short8*)(x_t + cb.w + c0);
                short8 r;
                #pragma unroll
                for (int e = 0; e < 8; ++e) {
                    float f = cw.x * bf2f((unsigned short)v0[e]);
                    f = fmaf(cw.y, bf2f((unsigned short)v1[e]), f);
                    f = fmaf(cw.z, bf2f((unsigned short)v2[e]), f);
                    f = fmaf(cw.w, bf2f((unsigned short)v3[e]), f);
                    r[e] = (short)f2bf(f);
                }
                int off = px * 128 + c8 * 16; off ^= (px & 7) << 4;
                *(short8*)(As + off) = r;
            }
            __syncthreads();
            // ---- MFMA: wave tile 32px x 64o ----
            int kb = (lane >> 4) << 4;
            int r0 = lane & 15;
            short8 a[2][2];
            #pragma unroll
            for (int m = 0; m < 2; ++m)
                #pragma unroll
                for (int kh = 0; kh < 2; ++kh) {
                    int row = m * 16 + r0;
                    int ao = row * 128 + kh * 64 + kb; ao ^= (row & 7) << 4;
                    a[m][kh] = *(const short8*)(As + ao);
                }
            #pragma unroll
            for (int n = 0; n < 4; ++n) {
                int brow = wv * 64 + n * 16 + r0;
                #pragma unroll
                for (int kh = 0; kh < 2; ++kh) {
                    int bo = brow * 128 + kh * 64 + kb; bo ^= (brow & 7) << 4;
                    short8 bv = *(const short8*)(Bs + bo);
                    #pragma unroll
                    for (int m = 0; m < 2; ++m)
                        acc[m][n] = __builtin_amdgcn_mfma_f32_16x16x32_bf16(a[m][kh], bv, acc[m][n], 0, 0, 0);
                }
            }
            __syncthreads();
        }
    }
    // ---- epilogue: bias + tanh, NCHW float4 stores ----
    int o_ = lane & 15;
    int pr = (lane >> 4) << 2;
    #pragma unroll
    for (int n = 0; n < 4; ++n) {
        int o = wv * 64 + n * 16 + o_;
        float bia = b_conv[o];
        #pragma unroll
        for (int m = 0; m < 2; ++m) {
            int pxo = hw0 + m * 16 + pr;
            float4 v;
            v.x = tanhf(acc[m][n][0] + bia);
            v.y = tanhf(acc[m][n][1] + bia);
            v.z = tanhf(acc[m][n][2] + bia);
            v.w = tanhf(acc[m][n][3] + bia);
            *(float4*)(out + ((size_t)(b * OO + o)) * HWH + pxo) = v;
        }
    }
}

extern "C" void kernel_launch(void* const* d_in, const int* in_sizes, int n_in,
                              void* d_out, int out_size, void* d_ws, size_t ws_size,
                              hipStream_t stream) {
    const float* x      = (const float*)d_in[0];
    const float* w_off  = (const float*)d_in[1];
    const float* b_off  = (const float*)d_in[2];
    const float* w_conv = (const float*)d_in[3];
    const float* b_conv = (const float*)d_in[4];
    const float* fc1    = (const float*)d_in[5];
    const float* fc2    = (const float*)d_in[6];
    float* out = (float*)d_out;
    float* ws  = (float*)d_ws;

    float* y    = ws;                                  // 2048
    float* s    = y + 2048;                            // 2048
    float* offs = s + 2048;                            // 451584
    unsigned short* x_t  = (unsigned short*)(offs + 451584);   // 6422528 shorts
    unsigned short* wb_o = x_t + 6422528;                      // 73728 shorts
    unsigned short* wbp  = wb_o + 73728;                       // 589824 shorts (pre-swizzled)
    int4*   ci = (int4*)(wbp + 589824);                        // 225792 int4
    float4* cf = (float4*)(ci + 225792);                       // 225792 float4

    se_mean<<<BB * CC, 256, 0, stream>>>(x, y);
    se_fc<<<1, 256, 0, stream>>>(y, fc1, fc2, s);
    prep_wc<<<288, 256, 0, stream>>>(w_conv, wbp);
    prep_wo<<<288, 256, 0, stream>>>(w_off, wb_o);
    prep_xt<<<BB * 49 * 4, 256, 0, stream>>>(x, s, x_t);
    offset_mfma<<<BB * 49, 256, 0, stream>>>(x_t, wb_o, b_off, offs);
    coords_prep<<<882, 256, 0, stream>>>(offs, ci, cf);
    deform_mfma<<<BB * 98, 256, 0, stream>>>(x_t, ci, cf, wbp, b_conv, out);
}

// Round 4
// 140.432 us; speedup vs baseline: 9.1470x; 1.0134x over previous
//
#include <hip/hip_runtime.h>
#include <math.h>

typedef __attribute__((ext_vector_type(8))) short short8;
typedef __attribute__((ext_vector_type(4))) float f32x4;

#define BB 8
#define CC 256
#define OO 256
#define HH 56
#define WW 56
#define HWH 3136
#define RED 16

__device__ inline unsigned short f2bf(float f) {
    unsigned u = __builtin_bit_cast(unsigned, f);
    u = (u + 0x7fffu + ((u >> 16) & 1u)) >> 16;
    return (unsigned short)u;
}
__device__ inline float bf2f(unsigned short h) {
    return __builtin_bit_cast(float, ((unsigned)h) << 16);
}
__device__ inline unsigned cvtpk(float lo, float hi) {
    unsigned r;
    asm("v_cvt_pk_bf16_f32 %0, %1, %2" : "=v"(r) : "v"(lo), "v"(hi));
    return r;
}
__device__ inline float fast_tanh(float x) {
    float e = __expf(2.0f * x);
    return 1.0f - 2.0f / (e + 1.0f);
}

// ---------------- SE: mean over H,W ----------------
__global__ __launch_bounds__(256) void se_mean(const float* __restrict__ x, float* __restrict__ y) {
    int bc = blockIdx.x;
    const float4* p = (const float4*)(x + (size_t)bc * HWH);
    float sum = 0.f;
    for (int i = threadIdx.x; i < HWH / 4; i += 256) {
        float4 v = p[i];
        sum += v.x + v.y + v.z + v.w;
    }
    __shared__ float sm[4];
    for (int off = 32; off > 0; off >>= 1) sum += __shfl_down(sum, off);
    if ((threadIdx.x & 63) == 0) sm[threadIdx.x >> 6] = sum;
    __syncthreads();
    if (threadIdx.x == 0) y[bc] = (sm[0] + sm[1] + sm[2] + sm[3]) * (1.0f / HWH);
}

// ---------------- SE: fc1->relu->fc2->sigmoid ----------------
__global__ __launch_bounds__(256) void se_fc(const float* __restrict__ y, const float* __restrict__ fc1,
                                             const float* __restrict__ fc2, float* __restrict__ s) {
    __shared__ float hbuf[BB * RED];
    int t = threadIdx.x;
    if (t < BB * RED) {
        int b = t / RED, r = t % RED;
        float acc = 0.f;
        for (int c = 0; c < CC; ++c) acc += y[b * CC + c] * fc1[r * CC + c];
        hbuf[t] = fmaxf(acc, 0.f);
    }
    __syncthreads();
    for (int i = t; i < BB * CC; i += 256) {
        int b = i / CC, c = i % CC;
        float acc = 0.f;
        #pragma unroll
        for (int r = 0; r < RED; ++r) acc += hbuf[b * RED + r] * fc2[c * RED + r];
        s[i] = 1.0f / (1.0f + expf(-acc));
    }
}

// ---------------- NCHW f32 -> NHWC bf16, scaled by s ----------------
__global__ __launch_bounds__(256) void prep_xt(const float* __restrict__ x, const float* __restrict__ s,
                                               unsigned short* __restrict__ x_t) {
    __shared__ float t[64][65];
    int blk = blockIdx.x;
    int ct = blk & 3;
    int hwt = (blk >> 2) % 49;
    int b = blk / (4 * 49);
    int c0 = ct * 64, hw0 = hwt * 64;
    int tid = threadIdx.x;
    const float* xb = x + ((size_t)(b * CC + c0)) * HWH + hw0;
    #pragma unroll
    for (int it = 0; it < 16; ++it) {
        int idx = it * 256 + tid;
        int c = idx >> 6, px = idx & 63;
        t[c][px] = xb[(size_t)c * HWH + px];
    }
    __syncthreads();
    unsigned short* xo = x_t + ((size_t)(b * HWH + hw0)) * CC + c0;
    #pragma unroll
    for (int it = 0; it < 16; ++it) {
        int idx = it * 256 + tid;
        int px = idx >> 6, c = idx & 63;
        xo[(size_t)px * CC + c] = f2bf(t[c][px] * s[b * CC + c0 + c]);
    }
}

// ---------------- deform weights -> per-MFMA-fragment contiguous layout ----------------
// wbf[t(36)][wv(4)][f(8)=n*2+kh][lane(64)][e(8)] ; value = w_conv[o][c][kk] with
// o = wv*64 + n*16 + (lane&15), c = (t&3)*64 + kh*32 + ((lane>>4)<<3) + e, kk = t>>2
__global__ __launch_bounds__(256) void prep_wcf(const float* __restrict__ w_conv, unsigned short* __restrict__ wbf) {
    int idx = blockIdx.x * 256 + threadIdx.x;   // 73728
    int lane = idx & 63;
    int f = (idx >> 6) & 7;
    int wv4 = (idx >> 9) & 3;
    int t = idx >> 11;
    int kk = t >> 2, cc = t & 3;
    int n = f >> 1, kh = f & 1;
    int o = wv4 * 64 + n * 16 + (lane & 15);
    int cb = cc * 64 + kh * 32 + ((lane >> 4) << 3);
    short8 r;
    #pragma unroll
    for (int e = 0; e < 8; ++e) r[e] = (short)f2bf(w_conv[(size_t)(o * 256 + cb + e) * 9 + kk]);
    *(short8*)(wbf + (size_t)idx * 8) = r;
}

// ---------------- offset weights -> [kk][o][c] bf16 (o padded to 32) ----------------
__global__ __launch_bounds__(256) void prep_wo(const float* __restrict__ w_off, unsigned short* __restrict__ wb) {
    int idx = blockIdx.x * 256 + threadIdx.x;    // 9*32*256
    int kk = idx >> 13;
    int o = (idx >> 8) & 31;
    int c = idx & 255;
    wb[idx] = (o < 18) ? f2bf(w_off[((o << 8) + c) * 9 + kk]) : (unsigned short)0;
}

// ---------------- offset conv via MFMA: M=64px x N=32(pad18) x K=2304 ----------------
__global__ __launch_bounds__(256) void offset_mfma(const unsigned short* __restrict__ x_t,
                                                   const unsigned short* __restrict__ wb,
                                                   const float* __restrict__ b_off,
                                                   float* __restrict__ offs) {
    __shared__ __align__(16) char As[64 * 128];
    __shared__ __align__(16) char Bs2[32 * 128];
    int blk = blockIdx.x;
    int b = blk / 49;
    int hw0 = (blk % 49) * 64;
    int tid = threadIdx.x;
    int lane = tid & 63, wv = tid >> 6;
    f32x4 zero = {0.f, 0.f, 0.f, 0.f};
    f32x4 acc[2] = {zero, zero};
    for (int kk = 0; kk < 9; ++kk) {
        int di = kk / 3 - 1, dj = kk % 3 - 1;
        for (int cc = 0; cc < 4; ++cc) {
            int c0 = cc * 64;
            #pragma unroll
            for (int it = 0; it < 2; ++it) {
                int item = it * 256 + tid;
                int px = item >> 3, c8 = item & 7;
                int hw = hw0 + px, h = hw / 56, w = hw - h * 56;
                int hh = h + di, ww = w + dj;
                short8 v = {0, 0, 0, 0, 0, 0, 0, 0};
                if (hh >= 0 && hh < 56 && ww >= 0 && ww < 56)
                    v = *(const short8*)(x_t + (((size_t)(b * HWH + hh * 56 + ww)) << 8) + c0 + c8 * 8);
                int off = px * 128 + c8 * 16; off ^= (px & 7) << 4;
                *(short8*)(As + off) = v;
            }
            {
                int o = tid >> 3, c8 = tid & 7;
                short8 v = *(const short8*)(wb + kk * 8192 + o * 256 + c0 + c8 * 8);
                int off = o * 128 + c8 * 16; off ^= (o & 7) << 4;
                *(short8*)(Bs2 + off) = v;
            }
            __syncthreads();
            int arow = wv * 16 + (lane & 15);
            int kb = (lane >> 4) << 4;
            #pragma unroll
            for (int kh = 0; kh < 2; ++kh) {
                int ao = arow * 128 + kh * 64 + kb; ao ^= (arow & 7) << 4;
                short8 a = *(const short8*)(As + ao);
                #pragma unroll
                for (int n = 0; n < 2; ++n) {
                    int brow = n * 16 + (lane & 15);
                    int bo = brow * 128 + kh * 64 + kb; bo ^= (brow & 7) << 4;
                    short8 bv = *(const short8*)(Bs2 + bo);
                    acc[n] = __builtin_amdgcn_mfma_f32_16x16x32_bf16(a, bv, acc[n], 0, 0, 0);
                }
            }
            __syncthreads();
        }
    }
    int o_ = lane & 15;
    int prow = wv * 16 + ((lane >> 4) << 2);
    #pragma unroll
    for (int n = 0; n < 2; ++n) {
        int o = n * 16 + o_;
        if (o < 18) {
            float bia = b_off[o];
            #pragma unroll
            for (int r = 0; r < 4; ++r)
                offs[((size_t)(b * 18 + o)) * HWH + hw0 + prow + r] = acc[n][r] + bia;
        }
    }
}

// ---------------- precompute bilinear coords: bases (int4) + weights (float4) ----------------
__global__ __launch_bounds__(256) void coords_prep(const float* __restrict__ offs,
                                                   int4* __restrict__ ci, float4* __restrict__ cf) {
    int idx = blockIdx.x * 256 + threadIdx.x;    // 8*9*3136 = 225792
    int hw = idx % 3136;
    int t = idx / 3136;
    int kk = t % 9;
    int b = t / 9;
    int h = hw / 56, w = hw - h * 56;
    float dy = offs[((size_t)(b * 18 + kk * 2)) * HWH + hw];
    float dx = offs[((size_t)(b * 18 + kk * 2 + 1)) * HWH + hw];
    float ys = (float)(h - 1 + kk / 3) + dy;
    float xs = (float)(w - 1 + kk % 3) + dx;
    float y0f = floorf(ys), x0f = floorf(xs);
    float wy = ys - y0f, wx = xs - x0f;
    int y0 = (int)y0f, x0 = (int)x0f;
    int bi[4]; float wt[4];
    #pragma unroll
    for (int j = 0; j < 4; ++j) {
        int yj = y0 + (j >> 1), xj = x0 + (j & 1);
        bool val = yj >= 0 && yj < 56 && xj >= 0 && xj < 56;
        int yc = min(max(yj, 0), 55), xc = min(max(xj, 0), 55);
        wt[j] = val ? ((j >> 1) ? wy : 1.f - wy) * ((j & 1) ? wx : 1.f - wx) : 0.f;
        bi[j] = (b * HWH + yc * 56 + xc) << 8;
    }
    ci[idx] = make_int4(bi[0], bi[1], bi[2], bi[3]);
    cf[idx] = make_float4(wt[0], wt[1], wt[2], wt[3]);
}

// ---------------- deformable conv: 64px x 256o tiles, pipelined, B from global frags ----------------
#define LDB(DST, T) { \
    const unsigned short* _p = wbB + (size_t)(T) * 16384; \
    _Pragma("unroll") \
    for (int _f = 0; _f < 8; ++_f) DST[_f] = *(const short8*)(_p + _f * 512); }

#define LDA(DST, T, CB) { \
    int _c0 = ((T) & 3) * 64 + cg * 16; \
    DST[0] = *(const short8*)(x_t + (CB).x + _c0); \
    DST[1] = *(const short8*)(x_t + (CB).x + _c0 + 8); \
    DST[2] = *(const short8*)(x_t + (CB).y + _c0); \
    DST[3] = *(const short8*)(x_t + (CB).y + _c0 + 8); \
    DST[4] = *(const short8*)(x_t + (CB).z + _c0); \
    DST[5] = *(const short8*)(x_t + (CB).z + _c0 + 8); \
    DST[6] = *(const short8*)(x_t + (CB).w + _c0); \
    DST[7] = *(const short8*)(x_t + (CB).w + _c0 + 8); }

#define AVW(AV, CW, PAR) { \
    float _f[16]; \
    _Pragma("unroll") for (int _e = 0; _e < 16; ++_e) _f[_e] = 0.f; \
    _Pragma("unroll") for (int _j = 0; _j < 4; ++_j) { \
        float _w = ((_j == 0) ? (CW).x : (_j == 1) ? (CW).y : (_j == 2) ? (CW).z : (CW).w); \
        _Pragma("unroll") for (int _h = 0; _h < 2; ++_h) { \
            short8 _v = AV[_j * 2 + _h]; \
            _Pragma("unroll") for (int _e = 0; _e < 8; ++_e) \
                _f[_h * 8 + _e] = fmaf(_w, bf2f((unsigned short)_v[_e]), _f[_h * 8 + _e]); \
        } } \
    unsigned _pk[8]; \
    _Pragma("unroll") for (int _q = 0; _q < 8; ++_q) _pk[_q] = cvtpk(_f[_q * 2], _f[_q * 2 + 1]); \
    *(uint4*)(As + (PAR) * 8192 + aw0) = make_uint4(_pk[0], _pk[1], _pk[2], _pk[3]); \
    *(uint4*)(As + (PAR) * 8192 + aw1) = make_uint4(_pk[4], _pk[5], _pk[6], _pk[7]); }

#define RDMFMA(PAR, BC) { \
    short8 _a[4][2]; \
    _Pragma("unroll") for (int _m = 0; _m < 4; ++_m) \
      _Pragma("unroll") for (int _kh = 0; _kh < 2; ++_kh) { \
        int _row = _m * 16 + r0; \
        int _ao = (_row * 128 + _kh * 64 + kb) ^ ((_row & 7) << 4); \
        _a[_m][_kh] = *(const short8*)(As + (PAR) * 8192 + _ao); } \
    _Pragma("unroll") for (int _n = 0; _n < 4; ++_n) \
      _Pragma("unroll") for (int _kh = 0; _kh < 2; ++_kh) \
        _Pragma("unroll") for (int _m = 0; _m < 4; ++_m) \
          acc[_m][_n] = __builtin_amdgcn_mfma_f32_16x16x32_bf16(_a[_m][_kh], BC[_n * 2 + _kh], acc[_m][_n], 0, 0, 0); }

#define STEP(PAR, BC, AVC, AVL) { \
    RDMFMA(PAR, BC); \
    if (t < 35) { \
        if (((t + 1) & 3) == 0) cwV = cwI; \
        AVW(AVC, cwV, (PAR) ^ 1); \
    } \
    __syncthreads(); \
    if (t < 34) { \
        int _t2 = t + 2; \
        if ((_t2 & 3) == 0) { int _k2 = _t2 >> 2; cbI = ci[cidx0 + _k2 * HWH]; cwI = cf[cidx0 + _k2 * HWH]; } \
        LDB(BC, _t2); \
        LDA(AVL, _t2, cbI); \
    } \
    ++t; }

__global__ __launch_bounds__(256, 2) void deform_mfma(const unsigned short* __restrict__ x_t,
                                                      const int4* __restrict__ ci,
                                                      const float4* __restrict__ cf,
                                                      const unsigned short* __restrict__ wbf,
                                                      const float* __restrict__ b_conv,
                                                      float* __restrict__ out) {
    __shared__ __align__(16) char As[16384];        // 2 x 8KB (64px x 128B)
    int blk = blockIdx.x;
    blk = (blk & 7) * 49 + (blk >> 3);              // XCD-bijective swizzle (392 = 8*49)
    int b = blk / 49;
    int hw0 = (blk % 49) * 64;
    int tid = threadIdx.x;
    int lane = tid & 63, wv = tid >> 6;
    int px = tid >> 2, cg = tid & 3;                // A-stage roles: 64px x 4 ch-groups of 16
    int r0 = lane & 15, kb = (lane >> 4) << 4;
    int awb = px * 128 + cg * 32;
    int aw0 = awb ^ ((px & 7) << 4);
    int aw1 = (awb + 16) ^ ((px & 7) << 4);
    int cidx0 = (b * 9) * HWH + hw0 + px;
    const unsigned short* wbB = wbf + (size_t)wv * 4096 + lane * 8;

    f32x4 zero = {0.f, 0.f, 0.f, 0.f};
    f32x4 acc[4][4];
    #pragma unroll
    for (int m = 0; m < 4; ++m)
        #pragma unroll
        for (int n = 0; n < 4; ++n) acc[m][n] = zero;

    int4 cbI = ci[cidx0];
    float4 cwI = cf[cidx0];
    float4 cwV = cwI;
    short8 bE[8], bO[8], avE[8], avO[8];

    // ---- prologue: A(0) -> As[0]; issue B(0),B(1),A(1) ----
    {
        short8 a0[8];
        LDA(a0, 0, cbI);
        LDB(bE, 0);
        LDB(bO, 1);
        LDA(avO, 1, cbI);
        AVW(a0, cwV, 0);
    }
    __syncthreads();

    int t = 0;
    #pragma unroll 1
    for (int it = 0; it < 18; ++it) {
        STEP(0, bE, avO, avE);
        STEP(1, bO, avE, avO);
    }

    // ---- epilogue: bias + tanh, NCHW float4 stores ----
    #pragma unroll
    for (int n = 0; n < 4; ++n) {
        int o = wv * 64 + n * 16 + r0;
        float bia = b_conv[o];
        #pragma unroll
        for (int m = 0; m < 4; ++m) {
            int pxo = hw0 + m * 16 + ((lane >> 4) << 2);
            float4 v;
            v.x = fast_tanh(acc[m][n][0] + bia);
            v.y = fast_tanh(acc[m][n][1] + bia);
            v.z = fast_tanh(acc[m][n][2] + bia);
            v.w = fast_tanh(acc[m][n][3] + bia);
            *(float4*)(out + ((size_t)(b * OO + o)) * HWH + pxo) = v;
        }
    }
}

extern "C" void kernel_launch(void* const* d_in, const int* in_sizes, int n_in,
                              void* d_out, int out_size, void* d_ws, size_t ws_size,
                              hipStream_t stream) {
    const float* x      = (const float*)d_in[0];
    const float* w_off  = (const float*)d_in[1];
    const float* b_off  = (const float*)d_in[2];
    const float* w_conv = (const float*)d_in[3];
    const float* b_conv = (const float*)d_in[4];
    const float* fc1    = (const float*)d_in[5];
    const float* fc2    = (const float*)d_in[6];
    float* out = (float*)d_out;
    float* ws  = (float*)d_ws;

    float* y    = ws;                                  // 2048
    float* s    = y + 2048;                            // 2048
    float* offs = s + 2048;                            // 451584
    unsigned short* x_t  = (unsigned short*)(offs + 451584);   // 6422528 shorts
    unsigned short* wb_o = x_t + 6422528;                      // 73728 shorts
    unsigned short* wbf  = wb_o + 73728;                       // 589824 shorts (frag layout)
    int4*   ci = (int4*)(wbf + 589824);                        // 225792 int4
    float4* cf = (float4*)(ci + 225792);                       // 225792 float4

    se_mean<<<BB * CC, 256, 0, stream>>>(x, y);
    se_fc<<<1, 256, 0, stream>>>(y, fc1, fc2, s);
    prep_wcf<<<288, 256, 0, stream>>>(w_conv, wbf);
    prep_wo<<<288, 256, 0, stream>>>(w_off, wb_o);
    prep_xt<<<BB * 49 * 4, 256, 0, stream>>>(x, s, x_t);
    offset_mfma<<<BB * 49, 256, 0, stream>>>(x_t, wb_o, b_off, offs);
    coords_prep<<<882, 256, 0, stream>>>(offs, ci, cf);
    deform_mfma<<<BB * 49, 256, 0, stream>>>(x_t, ci, cf, wbf, b_conv, out);
}